// Round 1
// 1215.492 us; speedup vs baseline: 1.1391x; 1.1391x over previous
//
#include <hip/hip_runtime.h>
#include <stdint.h>

#define TOKENS 4096          // B*S
#define HDIM   4096
#define IDIM   11008
#define WELEMS 45088768L     // 11008*4096 (all three weights same element count)

using i32x4 = __attribute__((ext_vector_type(4))) int;
using s8x16 = __attribute__((ext_vector_type(16))) signed char;

__device__ __forceinline__ void async_load16(const void* g, void* l) {
  __builtin_amdgcn_global_load_lds(
      (const __attribute__((address_space(1))) void*)g,
      (__attribute__((address_space(3))) void*)l, 16, 0, 0);
}

// stage a 128-row x 128-byte chunk (16 KiB) into LDS, 512 threads x 2 loads.
// LDS dest is linear (global_load_lds requirement); the XOR swizzle
// (slot ^= row&7) is applied to the GLOBAL source address instead (rule:
// linear dest + inverse-swizzled source + swizzled read).
__device__ __forceinline__ void stage128(
    const int8_t* __restrict__ g, long grow0, long ld, long kbase,
    int8_t* lds, int tid) {
  #pragma unroll
  for (int j = 0; j < 2; ++j) {
    const int idx  = j * 512 + tid;
    const int row  = idx >> 3;          // 0..127
    const int slot = idx & 7;           // 16B slot within 128B row
    const int8_t* src = g + (grow0 + row) * ld + kbase + ((slot ^ (row & 7)) << 4);
    async_load16(src, lds + idx * 16);
  }
}

// phase sync: counted vmcnt (never 0 in main loop) + raw barrier + lgkm drain
#define PH_SYNC() \
  asm volatile("s_waitcnt vmcnt(4)" ::: "memory"); \
  __builtin_amdgcn_s_barrier(); \
  asm volatile("s_waitcnt lgkmcnt(0)" ::: "memory"); \
  __builtin_amdgcn_sched_barrier(0); \
  __builtin_amdgcn_s_setprio(1)

#define PH_END() \
  __builtin_amdgcn_s_setprio(0); \
  __builtin_amdgcn_s_barrier()

// ---------------- weight |.| sum (fp64, deterministic-enough) ----------------
__global__ __launch_bounds__(256) void wsum_kernel(
    const float* __restrict__ w0, const float* __restrict__ w1,
    const float* __restrict__ w2, double* __restrict__ dsum) {
  const float* w = (blockIdx.y == 0) ? w0 : (blockIdx.y == 1) ? w1 : w2;
  const long n4 = WELEMS / 4;
  long i = (long)blockIdx.x * blockDim.x + threadIdx.x;
  const long stride = (long)gridDim.x * blockDim.x;
  double s = 0.0;
  for (; i < n4; i += stride) {
    float4 v = ((const float4*)w)[i];
    s += (double)fabsf(v.x); s += (double)fabsf(v.y);
    s += (double)fabsf(v.z); s += (double)fabsf(v.w);
  }
  __shared__ double red[256];
  red[threadIdx.x] = s;
  __syncthreads();
  for (int off = 128; off; off >>= 1) {
    if (threadIdx.x < (unsigned)off) red[threadIdx.x] += red[threadIdx.x + off];
    __syncthreads();
  }
  if (threadIdx.x == 0) atomicAdd(&dsum[blockIdx.y], red[0]);
}

__global__ void wscale_kernel(const double* __restrict__ dsum, double* __restrict__ wsc) {
  int i = threadIdx.x;
  if (i < 3) {
    double mean = dsum[i] / (double)WELEMS;
    wsc[i] = 1.0 / fmax(mean, 1e-5);
  }
}

// ---------------- weight ternary quant ----------------
__global__ __launch_bounds__(256) void wquant_kernel(
    const float* __restrict__ w0, const float* __restrict__ w1, const float* __restrict__ w2,
    int8_t* __restrict__ q0, int8_t* __restrict__ q1, int8_t* __restrict__ q2,
    const double* __restrict__ wsc) {
  const int wi = blockIdx.y;
  const float* w = (wi == 0) ? w0 : (wi == 1) ? w1 : w2;
  int8_t* q = (wi == 0) ? q0 : (wi == 1) ? q1 : q2;
  const double sc = wsc[wi];
  long c = (long)blockIdx.x * blockDim.x + threadIdx.x;   // 16-element chunk
  if (c * 16 >= WELEMS) return;
  const float4* src = (const float4*)(w + c * 16);
  s8x16 outv;
  #pragma unroll
  for (int j = 0; j < 4; ++j) {
    float4 v = src[j];
    double t0 = rint((double)v.x * sc); t0 = fmin(fmax(t0, -1.0), 1.0);
    double t1 = rint((double)v.y * sc); t1 = fmin(fmax(t1, -1.0), 1.0);
    double t2 = rint((double)v.z * sc); t2 = fmin(fmax(t2, -1.0), 1.0);
    double t3 = rint((double)v.w * sc); t3 = fmin(fmax(t3, -1.0), 1.0);
    outv[j*4+0] = (signed char)(int)t0; outv[j*4+1] = (signed char)(int)t1;
    outv[j*4+2] = (signed char)(int)t2; outv[j*4+3] = (signed char)(int)t3;
  }
  *(s8x16*)(q + c * 16) = outv;
}

// ---------------- per-token activation quant of x ----------------
__global__ __launch_bounds__(256) void xquant_kernel(
    const float* __restrict__ x, int8_t* __restrict__ xq, double* __restrict__ sx) {
  const int row = blockIdx.x;
  const float* xr = x + (long)row * HDIM;
  const float4* xr4 = (const float4*)xr;
  float m = 0.f;
  for (int i = threadIdx.x; i < HDIM / 4; i += 256) {
    float4 v = xr4[i];
    m = fmaxf(m, fmaxf(fmaxf(fabsf(v.x), fabsf(v.y)), fmaxf(fabsf(v.z), fabsf(v.w))));
  }
  __shared__ float red[256];
  red[threadIdx.x] = m;
  __syncthreads();
  for (int off = 128; off; off >>= 1) {
    if (threadIdx.x < (unsigned)off) red[threadIdx.x] = fmaxf(red[threadIdx.x], red[threadIdx.x + off]);
    __syncthreads();
  }
  __shared__ double s_sc;
  if (threadIdx.x == 0) {
    double sc = 127.0 / fmax((double)red[0], 1e-5);
    sx[row] = sc;
    s_sc = sc;
  }
  __syncthreads();
  const double sc = s_sc;
  s8x16 outv;
  #pragma unroll
  for (int j = 0; j < 4; ++j) {
    float4 v = xr4[threadIdx.x * 4 + j];
    double t0 = rint((double)v.x * sc); t0 = fmin(fmax(t0, -128.0), 127.0);
    double t1 = rint((double)v.y * sc); t1 = fmin(fmax(t1, -128.0), 127.0);
    double t2 = rint((double)v.z * sc); t2 = fmin(fmax(t2, -128.0), 127.0);
    double t3 = rint((double)v.w * sc); t3 = fmin(fmax(t3, -128.0), 127.0);
    outv[j*4+0] = (signed char)(int)t0; outv[j*4+1] = (signed char)(int)t1;
    outv[j*4+2] = (signed char)(int)t2; outv[j*4+3] = (signed char)(int)t3;
  }
  *(s8x16*)(xq + (long)row * HDIM + threadIdx.x * 16) = outv;
}

// ================= fused gate+up i8 GEMM (8-phase schedule) =================
// tile 256(M) x 128(N), K-step 128, 8 waves (4M x 2N), per-wave 64x64 per matrix.
// Double-buffered LDS (even tiles -> buf0, odd -> buf1), 128 KiB.
// Per phase: {ds_read frags | stage one 16KiB chunk | vmcnt(4) | barrier |
//             lgkmcnt(0) | 16 MFMA under setprio(1) | barrier}.

__device__ __forceinline__ void g1_rdA(const int8_t* buf, int mh, int abase0,
                                       int kq, int swl, i32x4 afr[2][2]) {
  #pragma unroll
  for (int m = 0; m < 2; ++m)
    #pragma unroll
    for (int ks = 0; ks < 2; ++ks)
      afr[m][ks] = *(const i32x4*)(buf + abase0 + m * 2048 + mh * 16384 +
                                   ((((ks << 2) | kq) ^ swl) << 4));
}

__device__ __forceinline__ void g1_rdB(const int8_t* buf, int bbase0,
                                       int kq, int swl, i32x4 bfr[4][2]) {
  #pragma unroll
  for (int n = 0; n < 4; ++n)
    #pragma unroll
    for (int ks = 0; ks < 2; ++ks)
      bfr[n][ks] = *(const i32x4*)(buf + bbase0 + n * 2048 +
                                   ((((ks << 2) | kq) ^ swl) << 4));
}

__device__ __forceinline__ void g1_mfma(i32x4 acc[4][4], const i32x4 afr[2][2],
                                        const i32x4 bfr[4][2], int mh) {
  #pragma unroll
  for (int ks = 0; ks < 2; ++ks)
    #pragma unroll
    for (int m = 0; m < 2; ++m)
      #pragma unroll
      for (int n = 0; n < 4; ++n)
        acc[mh*2+m][n] = __builtin_amdgcn_mfma_i32_16x16x64_i8(
            afr[m][ks], bfr[n][ks], acc[mh*2+m][n], 0, 0, 0);
}

__global__ __launch_bounds__(512, 2) void gemm1_kernel(
    const int8_t* __restrict__ Aq, const int8_t* __restrict__ Bg, const int8_t* __restrict__ Bu,
    const double* __restrict__ sx, const double* __restrict__ wsc,
    float* __restrict__ H, unsigned int* __restrict__ hmax) {
  __shared__ __align__(16) int8_t As[2][256 * 128];   // 64 KiB
  __shared__ __align__(16) int8_t Bgs[2][128 * 128];  // 32 KiB
  __shared__ __align__(16) int8_t Bus[2][128 * 128];  // 32 KiB
  __shared__ unsigned int smax[256];

  const int tid = threadIdx.x;
  const int l   = tid & 63;
  const int wid = tid >> 6;
  const int wr  = wid >> 1;      // 0..3 (M)
  const int wc  = wid & 1;       // 0..1 (N)
  const int mr  = l & 15;
  const int kq  = l >> 4;
  const int swl = l & 7;
  const int row0 = blockIdx.y * 256;
  const int col0 = blockIdx.x * 128;

  // A m-frag t: row = (t>>1)*128 + wr*32 + (t&1)*16 + mr
  const int abase0 = (wr * 32 + mr) * 128;
  // B n-frag n: col = wc*64 + n*16 + mr
  const int bbase0 = (wc * 64 + mr) * 128;

  if (tid < 256) smax[tid] = 0u;

  // prologue: stage tile 0 -> buf0 in consumption order A0, Bg, Bu, A1
  stage128(Aq, row0,        HDIM, 0, As[0],          tid);
  stage128(Bg, col0,        HDIM, 0, Bgs[0],         tid);
  stage128(Bu, col0,        HDIM, 0, Bus[0],         tid);
  stage128(Aq, row0 + 128,  HDIM, 0, As[0] + 16384,  tid);
  asm volatile("s_waitcnt vmcnt(4)" ::: "memory");   // A0,Bg,Bu landed
  __builtin_amdgcn_s_barrier();

  i32x4 accg[4][4], accu[4][4];
  #pragma unroll
  for (int i = 0; i < 4; ++i)
    #pragma unroll
    for (int j = 0; j < 4; ++j) { accg[i][j] = (i32x4){0,0,0,0}; accu[i][j] = (i32x4){0,0,0,0}; }
  i32x4 afr[2][2], bgf[4][2], buv[4][2];

  #pragma unroll 1
  for (int I = 0; I < 16; ++I) {                  // 32 K-tiles, 2 per iter
    const long k1 = (long)(2 * I + 1) * 128;      // odd tile -> buf1
    const long k2 = (2 * I + 2 < 32) ? (long)(2 * I + 2) * 128 : 0;  // ghost-wrap

    // ---- phase 0: consume buf0 (A mh0 + Bg), stage buf1.A0
    g1_rdA(As[0], 0, abase0, kq, swl, afr);
    g1_rdB(Bgs[0], bbase0, kq, swl, bgf);
    stage128(Aq, row0, HDIM, k1, As[1], tid);
    PH_SYNC();
    g1_mfma(accg, afr, bgf, 0);
    PH_END();
    // ---- phase 1: consume buf0.Bu, stage buf1.Bg
    g1_rdB(Bus[0], bbase0, kq, swl, buv);
    stage128(Bg, col0, HDIM, k1, Bgs[1], tid);
    PH_SYNC();
    g1_mfma(accu, afr, buv, 0);
    PH_END();
    // ---- phase 2: consume buf0 (A mh1), stage buf1.Bu
    g1_rdA(As[0], 1, abase0, kq, swl, afr);
    stage128(Bu, col0, HDIM, k1, Bus[1], tid);
    PH_SYNC();
    g1_mfma(accg, afr, bgf, 1);
    PH_END();
    // ---- phase 3: no reads, stage buf1.A1
    stage128(Aq, row0 + 128, HDIM, k1, As[1] + 16384, tid);
    PH_SYNC();
    g1_mfma(accu, afr, buv, 1);
    PH_END();
    // ---- phase 4: consume buf1 (A mh0 + Bg), stage buf0.A0 (tile 2I+2)
    g1_rdA(As[1], 0, abase0, kq, swl, afr);
    g1_rdB(Bgs[1], bbase0, kq, swl, bgf);
    stage128(Aq, row0, HDIM, k2, As[0], tid);
    PH_SYNC();
    g1_mfma(accg, afr, bgf, 0);
    PH_END();
    // ---- phase 5
    g1_rdB(Bus[1], bbase0, kq, swl, buv);
    stage128(Bg, col0, HDIM, k2, Bgs[0], tid);
    PH_SYNC();
    g1_mfma(accu, afr, buv, 0);
    PH_END();
    // ---- phase 6
    g1_rdA(As[1], 1, abase0, kq, swl, afr);
    stage128(Bu, col0, HDIM, k2, Bus[0], tid);
    PH_SYNC();
    g1_mfma(accg, afr, bgf, 1);
    PH_END();
    // ---- phase 7
    stage128(Aq, row0 + 128, HDIM, k2, As[0] + 16384, tid);
    PH_SYNC();
    g1_mfma(accu, afr, buv, 1);
    PH_END();
  }

  // epilogue: h = relu(g)^2 * u, row absmax
  const double swg = wsc[0], swu = wsc[1];
  #pragma unroll
  for (int t = 0; t < 4; ++t) {
    #pragma unroll
    for (int r = 0; r < 4; ++r) {
      const int lrow = (t >> 1) * 128 + wr * 32 + (t & 1) * 16 + kq * 4 + r;
      const long grow = row0 + lrow;
      const double sxr = sx[grow];
      const double dg = 1.0 / (sxr * swg);
      const double du = 1.0 / (sxr * swu);
      float am = 0.f;
      #pragma unroll
      for (int n = 0; n < 4; ++n) {
        const float g = (float)((double)accg[t][n][r] * dg);
        const float u = (float)((double)accu[t][n][r] * du);
        const float gr = g > 0.f ? g * g : 0.f;
        const float h = gr * u;
        H[grow * IDIM + col0 + wc * 64 + n * 16 + mr] = h;
        am = fmaxf(am, fabsf(h));
      }
      atomicMax(&smax[lrow], __float_as_uint(am));
    }
  }
  __syncthreads();
  if (tid < 256) atomicMax(&hmax[row0 + tid], smax[tid]);
}

// ---------------- quantize h per token ----------------
__global__ __launch_bounds__(256) void hquant_kernel(
    const float* __restrict__ H, int8_t* __restrict__ hq, const unsigned int* __restrict__ hmax) {
  const long c = (long)blockIdx.x * blockDim.x + threadIdx.x;
  const long nchunks = (long)TOKENS * IDIM / 16;
  if (c >= nchunks) return;
  const int row = (int)(c / (IDIM / 16));
  const double sc = 127.0 / fmax((double)__uint_as_float(hmax[row]), 1e-5);
  const float4* src = (const float4*)(H + c * 16);
  s8x16 outv;
  #pragma unroll
  for (int j = 0; j < 4; ++j) {
    float4 v = src[j];
    double t0 = rint((double)v.x * sc); t0 = fmin(fmax(t0, -128.0), 127.0);
    double t1 = rint((double)v.y * sc); t1 = fmin(fmax(t1, -128.0), 127.0);
    double t2 = rint((double)v.z * sc); t2 = fmin(fmax(t2, -128.0), 127.0);
    double t3 = rint((double)v.w * sc); t3 = fmin(fmax(t3, -128.0), 127.0);
    outv[j*4+0] = (signed char)(int)t0; outv[j*4+1] = (signed char)(int)t1;
    outv[j*4+2] = (signed char)(int)t2; outv[j*4+3] = (signed char)(int)t3;
  }
  *(s8x16*)(hq + c * 16) = outv;
}

// ================= down-proj i8 GEMM (8-phase schedule) =================
// tile 256x256, K-step 128, 8 waves (2M x 4N), per-wave 128x64.

__device__ __forceinline__ void g2_rdA(const int8_t* buf, int mh, int abase0,
                                       int kq, int swl, i32x4 afr[4][2]) {
  #pragma unroll
  for (int m = 0; m < 4; ++m)
    #pragma unroll
    for (int ks = 0; ks < 2; ++ks)
      afr[m][ks] = *(const i32x4*)(buf + abase0 + m * 2048 + mh * 16384 +
                                   ((((ks << 2) | kq) ^ swl) << 4));
}

__device__ __forceinline__ void g2_rdB(const int8_t* buf, int nh, int bbase0,
                                       int kq, int swl, i32x4 bfr[4][2]) {
  #pragma unroll
  for (int n = 0; n < 2; ++n)
    #pragma unroll
    for (int ks = 0; ks < 2; ++ks)
      bfr[nh*2+n][ks] = *(const i32x4*)(buf + bbase0 + n * 2048 + nh * 16384 +
                                        ((((ks << 2) | kq) ^ swl) << 4));
}

__device__ __forceinline__ void g2_mfma(i32x4 acc[8][4], const i32x4 afr[4][2],
                                        const i32x4 bfr[4][2], int mh, int nh) {
  #pragma unroll
  for (int ks = 0; ks < 2; ++ks)
    #pragma unroll
    for (int m = 0; m < 4; ++m)
      #pragma unroll
      for (int n = 0; n < 2; ++n)
        acc[mh*4+m][nh*2+n] = __builtin_amdgcn_mfma_i32_16x16x64_i8(
            afr[m][ks], bfr[nh*2+n][ks], acc[mh*4+m][nh*2+n], 0, 0, 0);
}

__global__ __launch_bounds__(512, 2) void gemm2_kernel(
    const int8_t* __restrict__ Aq, const int8_t* __restrict__ Bq,
    const unsigned int* __restrict__ hmax, const double* __restrict__ wsc,
    float* __restrict__ out) {
  __shared__ __align__(16) int8_t As[2][256 * 128];   // 64 KiB
  __shared__ __align__(16) int8_t Bs[2][256 * 128];   // 64 KiB

  const int tid = threadIdx.x;
  const int l   = tid & 63;
  const int wid = tid >> 6;
  const int wr  = wid >> 2;      // 0..1 (M)
  const int wc  = wid & 3;       // 0..3 (N)
  const int mr  = l & 15;
  const int kq  = l >> 4;
  const int swl = l & 7;
  const int row0 = blockIdx.y * 256;
  const int col0 = blockIdx.x * 256;

  // A m-frag t: row = (t>>2)*128 + wr*64 + (t&3)*16 + mr
  const int abase0 = (wr * 64 + mr) * 128;
  // B n-frag n: col = (n>>1)*128 + wc*32 + (n&1)*16 + mr
  const int bbase0 = (wc * 32 + mr) * 128;

  // prologue: stage tile 0 -> buf0 in consumption order A-hi, B-hi, B-lo, A-lo
  stage128(Aq, row0,        IDIM, 0, As[0],          tid);
  stage128(Bq, col0,        IDIM, 0, Bs[0],          tid);
  stage128(Bq, col0 + 128,  IDIM, 0, Bs[0] + 16384,  tid);
  stage128(Aq, row0 + 128,  IDIM, 0, As[0] + 16384,  tid);
  asm volatile("s_waitcnt vmcnt(4)" ::: "memory");
  __builtin_amdgcn_s_barrier();

  i32x4 acc[8][4];
  #pragma unroll
  for (int i = 0; i < 8; ++i)
    #pragma unroll
    for (int j = 0; j < 4; ++j) acc[i][j] = (i32x4){0,0,0,0};
  i32x4 afr[4][2], bfr[4][2];

  #pragma unroll 1
  for (int I = 0; I < 43; ++I) {                  // 86 K-tiles, 2 per iter
    const long k1 = (long)(2 * I + 1) * 128;
    const long k2 = (2 * I + 2 < 86) ? (long)(2 * I + 2) * 128 : 0;

    // ---- phase 0: A mh0 + B nh0 from buf0; stage buf1.A-hi
    g2_rdA(As[0], 0, abase0, kq, swl, afr);
    g2_rdB(Bs[0], 0, bbase0, kq, swl, bfr);
    stage128(Aq, row0, IDIM, k1, As[1], tid);
    PH_SYNC();
    g2_mfma(acc, afr, bfr, 0, 0);
    PH_END();
    // ---- phase 1: B nh1; stage buf1.B-hi
    g2_rdB(Bs[0], 1, bbase0, kq, swl, bfr);
    stage128(Bq, col0, IDIM, k1, Bs[1], tid);
    PH_SYNC();
    g2_mfma(acc, afr, bfr, 0, 1);
    PH_END();
    // ---- phase 2: A mh1; stage buf1.B-lo
    g2_rdA(As[0], 1, abase0, kq, swl, afr);
    stage128(Bq, col0 + 128, IDIM, k1, Bs[1] + 16384, tid);
    PH_SYNC();
    g2_mfma(acc, afr, bfr, 1, 0);
    PH_END();
    // ---- phase 3: stage buf1.A-lo
    stage128(Aq, row0 + 128, IDIM, k1, As[1] + 16384, tid);
    PH_SYNC();
    g2_mfma(acc, afr, bfr, 1, 1);
    PH_END();
    // ---- phase 4
    g2_rdA(As[1], 0, abase0, kq, swl, afr);
    g2_rdB(Bs[1], 0, bbase0, kq, swl, bfr);
    stage128(Aq, row0, IDIM, k2, As[0], tid);
    PH_SYNC();
    g2_mfma(acc, afr, bfr, 0, 0);
    PH_END();
    // ---- phase 5
    g2_rdB(Bs[1], 1, bbase0, kq, swl, bfr);
    stage128(Bq, col0, IDIM, k2, Bs[0], tid);
    PH_SYNC();
    g2_mfma(acc, afr, bfr, 0, 1);
    PH_END();
    // ---- phase 6
    g2_rdA(As[1], 1, abase0, kq, swl, afr);
    stage128(Bq, col0 + 128, IDIM, k2, Bs[0] + 16384, tid);
    PH_SYNC();
    g2_mfma(acc, afr, bfr, 1, 0);
    PH_END();
    // ---- phase 7
    stage128(Aq, row0 + 128, IDIM, k2, As[0] + 16384, tid);
    PH_SYNC();
    g2_mfma(acc, afr, bfr, 1, 1);
    PH_END();
  }

  const double swd = wsc[2];
  #pragma unroll
  for (int t = 0; t < 8; ++t) {
    #pragma unroll
    for (int r = 0; r < 4; ++r) {
      const int lrow = (t >> 2) * 128 + wr * 64 + (t & 3) * 16 + kq * 4 + r;
      const long grow = row0 + lrow;
      const double shr = 127.0 / fmax((double)__uint_as_float(hmax[grow]), 1e-5);
      const double inv = 1.0 / (shr * swd);
      #pragma unroll
      for (int n = 0; n < 4; ++n)
        out[grow * HDIM + col0 + (n >> 1) * 128 + wc * 32 + (n & 1) * 16 + mr] =
            (float)((double)acc[t][n][r] * inv);
    }
  }
}

extern "C" void kernel_launch(void* const* d_in, const int* in_sizes, int n_in,
                              void* d_out, int out_size, void* d_ws, size_t ws_size,
                              hipStream_t stream) {
  const float* x  = (const float*)d_in[0];
  const float* wg = (const float*)d_in[1];
  const float* wu = (const float*)d_in[2];
  const float* wd = (const float*)d_in[3];
  float* out = (float*)d_out;

  char* ws = (char*)d_ws;
  double*   dsum  = (double*)ws;                       // [4]   @0
  double*   wsc   = (double*)(ws + 32);                // [3]   @32
  double*   sx    = (double*)(ws + 64);                // [4096]@64
  unsigned* hmaxb = (unsigned*)(ws + 64 + TOKENS * 8); // [4096]@32832
  int8_t*   xq    = (int8_t*)(ws + 131072);
  int8_t*   wqg   = xq + (long)TOKENS * HDIM;
  int8_t*   wqu   = wqg + WELEMS;
  int8_t*   wqd   = wqu + WELEMS;
  int8_t*   hq    = wqd + WELEMS;
  float*    H     = (float*)(hq + WELEMS);
  const size_t needed = 131072 + (size_t)TOKENS * HDIM + 4 * (size_t)WELEMS
                      + (size_t)TOKENS * IDIM * sizeof(float);
  if (ws_size < needed) {
    hipMemsetAsync(d_out, 0, (size_t)out_size * sizeof(float), stream);
    return;
  }

  hipMemsetAsync(ws, 0, 65536, stream);  // zeros dsum + sx + hmax region

  { dim3 g(1024, 3); wsum_kernel<<<g, 256, 0, stream>>>(wg, wu, wd, dsum); }
  wscale_kernel<<<1, 64, 0, stream>>>(dsum, wsc);
  { dim3 g((unsigned)(WELEMS / (256 * 16)), 3);
    wquant_kernel<<<g, 256, 0, stream>>>(wg, wu, wd, wqg, wqu, wqd, wsc); }
  xquant_kernel<<<TOKENS, 256, 0, stream>>>(x, xq, sx);
  { dim3 g(IDIM / 128, TOKENS / 256);   // 86 x 16
    gemm1_kernel<<<g, 512, 0, stream>>>(xq, wqg, wqu, sx, wsc, H, hmaxb); }
  hquant_kernel<<<(unsigned)((long)TOKENS * IDIM / 16 / 256), 256, 0, stream>>>(H, hq, hmaxb);
  { dim3 g(HDIM / 256, TOKENS / 256);   // 16 x 16
    gemm2_kernel<<<g, 512, 0, stream>>>(hq, wqd, hmaxb, wsc, out); }
}